// Round 10
// baseline (1187.871 us; speedup 1.0000x reference)
//
#include <hip/hip_runtime.h>
#include <hip/hip_bf16.h>
#include <math.h>

#define NBATCH 1024
#define NT 120
#define NE 50
#define NH 300
#define NC 5
#define GH 1200
#define NKPAD 352      // K = NH + NE padded to 352
#define NSTRIP 15      // hidx strips of 20
#define HS 20          // hidx per strip
#define SCOL 80        // strip cols = 4*HS (gates interleaved: col = 4*hsub+g)
#define NGRP 16        // batch groups
#define BB 64          // batch rows per group
#define ASTR 376       // A_lds row stride in ushorts
#define WSTR 376
#define ZSTR 84        // z_lds row stride in floats (16B-aligned float4 reads)
#define HBSTR 304      // hbuf row stride in ushorts (608B rows)
#define HCH 76         // 8B chunks per hbuf row
typedef unsigned long long ull;

typedef __attribute__((ext_vector_type(8))) short short8;
typedef __attribute__((ext_vector_type(4))) float f32x4;
typedef __attribute__((ext_vector_type(4))) unsigned short us4;
typedef __attribute__((ext_vector_type(2))) unsigned short us2;

static __device__ __forceinline__ float bf2f(unsigned short u) {
    unsigned int x = ((unsigned int)u) << 16;
    return __builtin_bit_cast(float, x);
}
static __device__ __forceinline__ unsigned short f2bf(float f) {
    __hip_bfloat16 h = __float2bfloat16(f);   // RNE
    return __builtin_bit_cast(unsigned short, h);
}
static __device__ __forceinline__ float sigmoid_fast(float x) {
    return __builtin_amdgcn_rcpf(1.f + __expf(-x));
}
static __device__ __forceinline__ float tanh_fast(float x) {
    return 1.f - 2.f * __builtin_amdgcn_rcpf(1.f + __expf(2.f * x));
}
#define LGKM_FENCE() do { \
    asm volatile("s_waitcnt lgkmcnt(0)" ::: "memory"); \
    __builtin_amdgcn_sched_barrier(0); } while (0)

// ---------------------------------------------------------------------------
// Prepass: swizzle [Wh;Wx] into strip-major bf16: Wswz[s][j][k], j=4*hsub+g.
// ---------------------------------------------------------------------------
__global__ __launch_bounds__(256)
void wswz_kernel(const float* __restrict__ Wx, const float* __restrict__ Wh,
                 unsigned short* __restrict__ Wswz)
{
    int idx = blockIdx.x * 256 + threadIdx.x;
    if (idx >= NSTRIP * SCOL * NKPAD) return;
    int s = idx / (SCOL * NKPAD);
    int r = idx % (SCOL * NKPAD);
    int j = r / NKPAD, k = r % NKPAD;
    int col = (j & 3) * NH + s * HS + (j >> 2);
    float v = 0.f;
    if (k < NH)           v = Wh[k * GH + col];
    else if (k < NH + NE) v = Wx[(k - NH) * GH + col];
    Wswz[idx] = f2bf(v);
}

// ---------------------------------------------------------------------------
// Per-wave helpers (sync domain = (group g, wave w); 16 own rows each).
// Transport: PROVEN agent-scope relaxed 8B atomics (MALL path).
// ---------------------------------------------------------------------------
__device__ __forceinline__ void load_x_wave(const int* __restrict__ tokens,
        const float* __restrict__ emb, int b0, int w, int t,
        unsigned short* A_s, int lane)
{
    const int row = w * 16 + (lane >> 2), q = lane & 3;
    const int tok = tokens[(b0 + row) * NT + t];
    const float* er = emb + (size_t)tok * NE;
    unsigned short* dst = A_s + row * ASTR + NH;
#pragma unroll
    for (int m = 0; m < 7; ++m) {
        int f = q + 4 * m;
        if (f < 25) {
            float2 v = *(const float2*)(er + f * 2);
            us2 o; o.x = f2bf(v.x); o.y = f2bf(v.y);
            *(us2*)(dst + f * 2) = o;
        }
    }
}

__device__ __forceinline__ void store_h_wave(unsigned short* hb, int b0,
        int s, int w, const unsigned short* h_stage, int lane)
{
#pragma unroll
    for (int m = 0; m < 2; ++m) {
        const int c = lane + 64 * m;
        if (c < 80) {
            const int rl = c / 5, j = c % 5;
            ull val = *(const ull*)(h_stage + (w * 16 + rl) * HS + j * 4);
            ull* p = (ull*)(hb + (size_t)(b0 + w * 16 + rl) * HBSTR
                            + s * HS + j * 4);
            __hip_atomic_store(p, val, __ATOMIC_RELAXED,
                               __HIP_MEMORY_SCOPE_AGENT);
        }
    }
}

__device__ __forceinline__ void load_h_wave(const unsigned short* __restrict__ hb,
        int b0, int w, unsigned short* A_s, int lane)
{
    const ull* src = (const ull*)hb;
    ull v[19];
#pragma unroll
    for (int m = 0; m < 19; ++m) {
        const int idx = lane + 64 * m;
        if (idx < 1200) {
            const int rl = idx / 75, j = idx % 75;
            v[m] = __hip_atomic_load(src + (size_t)(b0 + w * 16 + rl) * HCH + j,
                                     __ATOMIC_RELAXED, __HIP_MEMORY_SCOPE_AGENT);
        }
    }
#pragma unroll
    for (int m = 0; m < 19; ++m) {
        const int idx = lane + 64 * m;
        if (idx < 1200) {
            const int rl = idx / 75, j = idx % 75;
            *(ull*)(A_s + (w * 16 + rl) * ASTR + j * 4) = v[m];
        }
    }
}

// CE for rows [lo,hi) (this wave ∩ this strip's share), wave-local.
__device__ __forceinline__ void ce_wave(bool doCE, int tc, int b0, int lo,
        int hi, const unsigned short* A_s, const float* U_s,
        const float* b2r, const int* __restrict__ labels,
        const int* __restrict__ mask, float* __restrict__ ce_arr, int lane)
{
    if (!doCE || lo >= hi) return;
    const int ridx = lane >> 2, part = lane & 3;
    const int row = lo + ridx;
    const bool act = (row < hi) && (ridx < hi - lo);
    float L0 = 0.f, L1 = 0.f, L2 = 0.f, L3 = 0.f, L4 = 0.f;
    if (act) {
        const int k0 = part * 76;
        const int n4 = (part < 3) ? 19 : 18;
        const unsigned short* ar = A_s + row * ASTR + k0;
        for (int c4 = 0; c4 < n4; ++c4) {
            us4 hv4 = *(const us4*)(ar + c4 * 4);
#pragma unroll
            for (int e = 0; e < 4; ++e) {
                float hv = bf2f(hv4[e]);
                const float* up = U_s + (k0 + c4 * 4 + e) * NC;
                L0 += hv * up[0]; L1 += hv * up[1]; L2 += hv * up[2];
                L3 += hv * up[3]; L4 += hv * up[4];
            }
        }
    }
    L0 += __shfl_xor(L0, 1, 64); L0 += __shfl_xor(L0, 2, 64);
    L1 += __shfl_xor(L1, 1, 64); L1 += __shfl_xor(L1, 2, 64);
    L2 += __shfl_xor(L2, 1, 64); L2 += __shfl_xor(L2, 2, 64);
    L3 += __shfl_xor(L3, 1, 64); L3 += __shfl_xor(L3, 2, 64);
    L4 += __shfl_xor(L4, 1, 64); L4 += __shfl_xor(L4, 2, 64);
    if (act && part == 0) {
        float L[5] = { L0 + b2r[0], L1 + b2r[1], L2 + b2r[2],
                       L3 + b2r[3], L4 + b2r[4] };
        float m = fmaxf(fmaxf(fmaxf(L[0], L[1]), fmaxf(L[2], L[3])), L[4]);
        float ssum = expf(L[0]-m)+expf(L[1]-m)+expf(L[2]-m)
                   + expf(L[3]-m)+expf(L[4]-m);
        float lse = m + logf(ssum);
        int bidx = b0 + row;
        int lab = labels[bidx * NT + tc];
        int mk  = mask[bidx * NT + tc];
        ce_arr[bidx * NT + tc] = mk ? (lse - L[lab]) : 0.f;
    }
}

// ---------------------------------------------------------------------------
// Persistent LSTM: 240 blocks = 16 groups x 15 strips; 4 wave-domains each.
// NO __syncthreads in the step loop — waves are self-paced.
// ---------------------------------------------------------------------------
__global__ __launch_bounds__(256, 1)
void lstm_persist(const int* __restrict__ tokens,
                  const int* __restrict__ labels,
                  const int* __restrict__ mask,
                  const float* __restrict__ emb,
                  const float* __restrict__ bias,
                  const float* __restrict__ U,
                  const float* __restrict__ b2,
                  const unsigned short* __restrict__ Wswz,
                  unsigned short* __restrict__ hbuf,
                  float* __restrict__ ce_arr,
                  int* __restrict__ flags)
{
    __shared__ unsigned short A_s[BB * ASTR];   // [h(0..299)|x(300..349)|pad]
    __shared__ unsigned short W_s[SCOL * WSTR];
    __shared__ __align__(16) unsigned short h_stage[BB * HS];
    __shared__ float z_s[BB * ZSTR];
    __shared__ float c_s[BB * HS];
    __shared__ float U_s[NH * NC];
    __shared__ float b_s[SCOL];

    const int tid  = threadIdx.x;
    const int g    = blockIdx.x & 15;
    const int s    = blockIdx.x >> 4;
    const int b0   = g * BB;
    const int w    = tid >> 6;
    const int lane = tid & 63;
    const int c15  = lane & 15;
    const int kq   = lane >> 4;
    const int r0   = (s * BB) / NSTRIP;
    const int r1   = ((s + 1) * BB) / NSTRIP;
    const int lo   = max(r0, w * 16);          // this wave's CE slice
    const int hi   = min(r1, w * 16 + 16);

    // ---- one-time init (block-wide, single barrier below) ----
    for (int idx = tid; idx < SCOL * 44; idx += 256) {
        int j = idx / 44, ch = idx % 44;
        *(uint4*)(W_s + j * WSTR + ch * 8) =
            *(const uint4*)(Wswz + (size_t)s * SCOL * NKPAD + j * NKPAD + ch * 8);
    }
    for (int idx = tid; idx < BB * NH; idx += 256) {
        int row = idx / NH, k = idx % NH;
        A_s[row * ASTR + k] = 0;
    }
    for (int idx = tid; idx < BB * 26; idx += 256) {
        int row = idx / 26, k = 350 + idx % 26;
        A_s[row * ASTR + k] = 0;
    }
    for (int idx = tid; idx < BB * HS; idx += 256) c_s[idx] = 0.f;
    for (int idx = tid; idx < NH * NC; idx += 256) U_s[idx] = U[idx];
    if (tid < SCOL) b_s[tid] = bias[(tid & 3) * NH + s * HS + (tid >> 2)];
    float b2r[5];
#pragma unroll
    for (int c = 0; c < 5; ++c) b2r[c] = b2[c];
    load_x_wave(tokens, emb, b0, w, 0, A_s, lane);
    __syncthreads();   // the ONLY block barrier

    const unsigned short* Ab = A_s + (w * 16 + c15) * ASTR + kq * 8;
    const unsigned short* Wb = W_s + c15 * WSTR + kq * 8;

    for (int t = 0; t < NT; ++t) {
        // ---- 1) z (own 16 rows x 80 cols) ----
        f32x4 acc[5];
#pragma unroll
        for (int n = 0; n < 5; ++n) acc[n] = (f32x4){0.f, 0.f, 0.f, 0.f};
#pragma unroll
        for (int ks = 0; ks < 11; ++ks) {
            short8 av = *(const short8*)(Ab + ks * 32);
#pragma unroll
            for (int n = 0; n < 5; ++n) {
                short8 bv = *(const short8*)(Wb + n * 16 * WSTR + ks * 32);
                acc[n] = __builtin_amdgcn_mfma_f32_16x16x32_bf16(av, bv, acc[n], 0, 0, 0);
            }
        }
#pragma unroll
        for (int n = 0; n < 5; ++n)
#pragma unroll
            for (int j = 0; j < 4; ++j)
                z_s[(w * 16 + kq * 4 + j) * ZSTR + n * 16 + c15] = acc[n][j];
        LGKM_FENCE();

        // ---- 2) x gather t+1 (own rows; A_s x-region already consumed) ----
        if (t + 1 < NT) load_x_wave(tokens, emb, b0, w, t + 1, A_s, lane);

        // ---- 3) cell update (own rows) ----
#pragma unroll
        for (int ii = 0; ii < 5; ++ii) {
            int idxl = lane * 5 + ii;            // 0..319
            int rl = idxl / HS, h = idxl % HS;
            int grow = w * 16 + rl;
            f32x4 z4 = *(f32x4*)(z_s + grow * ZSTR + h * 4);
            float zi = z4[0] + b_s[4 * h + 0];
            float zj = z4[1] + b_s[4 * h + 1];
            float zf = z4[2] + b_s[4 * h + 2];
            float zo = z4[3] + b_s[4 * h + 3];
            int cidx = w * 320 + idxl;
            float co = c_s[cidx];
            float fg = sigmoid_fast(zf + 1.f);   // forget bias 1.0
            float ig = sigmoid_fast(zi);
            float og = sigmoid_fast(zo);
            float cn = fg * co + ig * tanh_fast(zj);
            float hn = og * tanh_fast(cn);
            c_s[cidx] = cn;
            h_stage[cidx] = f2bf(hn);
        }
        LGKM_FENCE();

        // ---- 4) own-row h store + drain ----
        unsigned short* hb = hbuf + (size_t)(t & 1) * (NBATCH * HBSTR);
        store_h_wave(hb, b0, s, w, h_stage, lane);
        asm volatile("s_waitcnt vmcnt(0)" ::: "memory");

        // ---- 5) monotonic flag: (g,s,w) = t+1 ----
        if (lane == 0)
            __hip_atomic_store(flags + g * 64 + s * 4 + w, t + 1,
                               __ATOMIC_RELAXED, __HIP_MEMORY_SCOPE_AGENT);

        // ---- 6) CE(t-1) overlap (h_{t-1} still in own A_s rows) ----
        ce_wave(t >= 1, t - 1, b0, lo, hi, A_s, U_s, b2r,
                labels, mask, ce_arr, lane);

        // ---- 7) poll the 15 wave-w flags (guarded) ----
        {
            const int* fbase = flags + g * 64 + w;
            int done = (lane >= NSTRIP);
            int gu = 0;
            while (true) {
                if (!done) {
                    int fv = __hip_atomic_load(fbase + lane * 4,
                                               __ATOMIC_RELAXED,
                                               __HIP_MEMORY_SCOPE_AGENT);
                    done = (fv >= t + 1);
                }
                if (__ballot(done) == ~0ull) break;
                if (++gu > (1 << 20)) break;
                __builtin_amdgcn_s_sleep(2);
            }
        }

        // ---- 8) pull own 16 rows of h_t ----
        load_h_wave(hb, b0, w, A_s, lane);
        LGKM_FENCE();
    }

    // ---- CE for final step ----
    ce_wave(true, NT - 1, b0, lo, hi, A_s, U_s, b2r, labels, mask, ce_arr, lane);
}

// ---------------------------------------------------------------------------
// Deterministic two-stage reduction: sum(ce) / sum(mask).
// ---------------------------------------------------------------------------
__global__ __launch_bounds__(256)
void reduce1_kernel(const float* __restrict__ ce_arr,
                    const int* __restrict__ mask,
                    float* __restrict__ pce, float* __restrict__ pm)
{
    __shared__ float s_ce[256];
    __shared__ float s_m[256];
    const int tid = threadIdx.x;
    const int lo = blockIdx.x * 480;     // 122880 / 256
    float ac = 0.f, am = 0.f;
    for (int i = lo + tid; i < lo + 480; i += 256) {
        ac += ce_arr[i];
        am += (float)mask[i];
    }
    s_ce[tid] = ac; s_m[tid] = am;
    __syncthreads();
    for (int r = 128; r > 0; r >>= 1) {
        if (tid < r) { s_ce[tid] += s_ce[tid + r]; s_m[tid] += s_m[tid + r]; }
        __syncthreads();
    }
    if (tid == 0) { pce[blockIdx.x] = s_ce[0]; pm[blockIdx.x] = s_m[0]; }
}

__global__ __launch_bounds__(256)
void reduce2_kernel(const float* __restrict__ pce,
                    const float* __restrict__ pm,
                    float* __restrict__ out)
{
    __shared__ float s_ce[256];
    __shared__ float s_m[256];
    const int tid = threadIdx.x;
    s_ce[tid] = pce[tid];
    s_m[tid]  = pm[tid];
    __syncthreads();
    for (int r = 128; r > 0; r >>= 1) {
        if (tid < r) { s_ce[tid] += s_ce[tid + r]; s_m[tid] += s_m[tid + r]; }
        __syncthreads();
    }
    if (tid == 0) out[0] = s_ce[0] / s_m[0];
}

// ---------------------------------------------------------------------------
extern "C" void kernel_launch(void* const* d_in, const int* in_sizes, int n_in,
                              void* d_out, int out_size, void* d_ws, size_t ws_size,
                              hipStream_t stream)
{
    const int*   tokens = (const int*)d_in[0];
    const int*   labels = (const int*)d_in[1];
    const int*   mask   = (const int*)d_in[2];
    const float* emb    = (const float*)d_in[3];
    const float* Wx     = (const float*)d_in[4];
    const float* Wh     = (const float*)d_in[5];
    const float* bias   = (const float*)d_in[6];
    const float* U      = (const float*)d_in[7];
    const float* b2     = (const float*)d_in[8];

    char* wsb = (char*)d_ws;
    unsigned short* Wswz = (unsigned short*)wsb;                      // 844800 B
    unsigned short* hbuf = (unsigned short*)(wsb + 844800);           // 1245184 B
    float* ce    = (float*)(wsb + 2089984);                           // 491520 B
    float* pce   = (float*)(wsb + 2581504);                           // 1024 B
    float* pm    = (float*)(wsb + 2582528);                           // 1024 B
    int*   flags = (int*)(wsb + 2583552);                             // 4096 B

    hipMemsetAsync(flags, 0, 4096, stream);
    wswz_kernel<<<(NSTRIP * SCOL * NKPAD + 255) / 256, 256, 0, stream>>>(Wx, Wh, Wswz);
    lstm_persist<<<NGRP * NSTRIP, 256, 0, stream>>>(
        tokens, labels, mask, emb, bias, U, b2, Wswz, hbuf, ce, flags);
    reduce1_kernel<<<256, 256, 0, stream>>>(ce, mask, pce, pm);
    reduce2_kernel<<<1, 256, 0, stream>>>(pce, pm, (float*)d_out);
}

// Round 11
// 900.750 us; speedup vs baseline: 1.3188x; 1.3188x over previous
//
#include <hip/hip_runtime.h>
#include <hip/hip_bf16.h>
#include <math.h>

#define NBATCH 1024
#define NT 120
#define NE 50
#define NH 300
#define NC 5
#define GH 1200
#define NKPAD 352      // K = NH + NE padded to 352
#define NSTRIP 15      // hidx strips of 20
#define HS 20          // hidx per strip
#define SCOL 80        // strip cols = 4*HS (gates interleaved: col = 4*hsub+g)
#define NGRP 16        // batch groups
#define BB 64          // batch rows per group
#define ASTR 376       // A_lds row stride in ushorts
#define WSTR 376
#define ZSTR 84        // z_lds row stride in floats (16B-aligned float4 reads)
#define HBSTR 304      // hbuf row stride in ushorts (608B rows)
typedef unsigned long long ull;

typedef __attribute__((ext_vector_type(8))) short short8;
typedef __attribute__((ext_vector_type(4))) float f32x4;
typedef __attribute__((ext_vector_type(2))) unsigned short us2;

static __device__ __forceinline__ float bf2f(unsigned short u) {
    unsigned int x = ((unsigned int)u) << 16;
    return __builtin_bit_cast(float, x);
}
static __device__ __forceinline__ unsigned short f2bf(float f) {
    __hip_bfloat16 h = __float2bfloat16(f);   // RNE
    return __builtin_bit_cast(unsigned short, h);
}
static __device__ __forceinline__ float sigmoid_fast(float x) {
    return __builtin_amdgcn_rcpf(1.f + __expf(-x));
}
static __device__ __forceinline__ float tanh_fast(float x) {
    return 1.f - 2.f * __builtin_amdgcn_rcpf(1.f + __expf(2.f * x));
}

// ---------------------------------------------------------------------------
// Prepass: swizzle [Wh;Wx] into strip-major bf16: Wswz[s][j][k], j=4*hsub+g.
// ---------------------------------------------------------------------------
__global__ __launch_bounds__(256)
void wswz_kernel(const float* __restrict__ Wx, const float* __restrict__ Wh,
                 unsigned short* __restrict__ Wswz)
{
    int idx = blockIdx.x * 256 + threadIdx.x;
    if (idx >= NSTRIP * SCOL * NKPAD) return;
    int s = idx / (SCOL * NKPAD);
    int r = idx % (SCOL * NKPAD);
    int j = r / NKPAD, k = r % NKPAD;
    int col = (j & 3) * NH + s * HS + (j >> 2);
    float v = 0.f;
    if (k < NH)           v = Wh[k * GH + col];
    else if (k < NH + NE) v = Wx[(k - NH) * GH + col];
    Wswz[idx] = f2bf(v);
}

// h strip store: 320 coalesced 8B agent-scope stores from the LDS stage.
__device__ __forceinline__ void store_h(unsigned short* hb, int b0, int st,
                                        const unsigned short* h_stage, int tid)
{
#pragma unroll
    for (int m = 0; m < 2; ++m) {
        const int c = tid + m * 256;
        if (c < 320) {
            const int row = c / 5, j = c % 5;
            ull val = *(const ull*)(h_stage + row * HS + j * 4);
            ull* p = (ull*)(hb + (size_t)(b0 + row) * HBSTR + st * HS + j * 4);
            __hip_atomic_store(p, val, __ATOMIC_RELAXED,
                               __HIP_MEMORY_SCOPE_AGENT);
        }
    }
}

__device__ __forceinline__ void load_x(const int* __restrict__ tokens,
                                       const float* __restrict__ emb,
                                       int b0, int t, unsigned short* A_s, int tid)
{
    const int row = tid >> 2, q = tid & 3;
    const int tok = tokens[(b0 + row) * NT + t];
    const float* er = emb + (size_t)tok * NE;
    unsigned short* dst = A_s + row * ASTR + NH;   // x at k=300..349
    for (int m = 0; m < 7; ++m) {
        int f = q + 4 * m;                  // float2 index 0..24
        if (f < 25) {
            float2 v = *(const float2*)(er + f * 2);
            us2 o; o.x = f2bf(v.x); o.y = f2bf(v.y);
            *(us2*)(dst + f * 2) = o;
        }
    }
}

// CE phase0: partial dot products over h. Waves 0-2 only (LDS+VALU only,
// NO VMEM -> safe between store-issue and vmcnt drain).
__device__ __forceinline__ void ce_phase0(bool doCE, int r0, int nr,
        const unsigned short* A_s, const float* U_s, float* llds, int tid)
{
    if (!doCE || tid >= 192) return;
    for (int item = tid; item < nr * 50; item += 192) {
        int i = item / 50, rem = item % 50, c = rem / 10, q = rem % 10;
        const unsigned short* ar = A_s + (r0 + i) * ASTR + q * 30;
        const float* up = U_s + q * 30 * NC + c;
        float acc = 0.f;
#pragma unroll
        for (int k = 0; k < 30; ++k) acc += bf2f(ar[k]) * up[k * NC];
        llds[i * 50 + c * 10 + q] = acc;
    }
}

// CE final: index idx in [0, nr). Reads ONLY llds (not A_s) -> safe to run
// concurrently with the A_s h-region reload.
__device__ __forceinline__ void ce_final(bool doCE, int tc, int b0, int r0,
        int nr, const float* b2r, const int* __restrict__ labels,
        const int* __restrict__ mask, float* __restrict__ ce_arr,
        const float* llds, int idx)
{
    if (!doCE || idx >= nr) return;
    const float* pp = llds + idx * 50;
    float L[5];
#pragma unroll
    for (int c = 0; c < 5; ++c) {
        float sum = 0.f;
#pragma unroll
        for (int q = 0; q < 10; ++q) sum += pp[c * 10 + q];
        L[c] = sum + b2r[c];
    }
    float m = fmaxf(fmaxf(fmaxf(L[0], L[1]), fmaxf(L[2], L[3])), L[4]);
    float ssum = expf(L[0]-m)+expf(L[1]-m)+expf(L[2]-m)+expf(L[3]-m)+expf(L[4]-m);
    float lse = m + logf(ssum);
    int bidx = b0 + r0 + idx;
    int lab = labels[bidx * NT + tc];
    int mk  = mask[bidx * NT + tc];
    ce_arr[bidx * NT + tc] = mk ? (lse - L[lab]) : 0.f;
}

// ---------------------------------------------------------------------------
// Persistent LSTM kernel: 240 blocks = 16 batch-groups x 15 strips.
// ---------------------------------------------------------------------------
__global__ __launch_bounds__(256, 1)
void lstm_persist(const int* __restrict__ tokens,
                  const int* __restrict__ labels,
                  const int* __restrict__ mask,
                  const float* __restrict__ emb,
                  const float* __restrict__ bias,
                  const float* __restrict__ U,
                  const float* __restrict__ b2,
                  const unsigned short* __restrict__ Wswz,
                  unsigned short* __restrict__ hbuf,
                  float* __restrict__ ce_arr,
                  int* __restrict__ flags)
{
    __shared__ unsigned short A_s[BB * ASTR];     // [h(0..299) | x(300..349) | 0]
    __shared__ unsigned short W_s[SCOL * WSTR];
    __shared__ __align__(16) unsigned short h_stage[BB * HS];
    __shared__ float z_s[BB * ZSTR];
    __shared__ float c_s[BB * HS];
    __shared__ float U_s[NH * NC];
    __shared__ float b_s[SCOL];
    __shared__ float llds[5 * 50];

    const int tid  = threadIdx.x;
    const int g    = blockIdx.x & 15;
    const int s    = blockIdx.x >> 4;
    const int b0   = g * BB;
    const int wave = tid >> 6;
    const int lane = tid & 63;
    const int c15  = lane & 15;
    const int kq   = lane >> 4;
    const int r0   = (s * BB) / NSTRIP;
    const int r1   = ((s + 1) * BB) / NSTRIP;
    const int nr   = r1 - r0;
    const int sp   = tid >> 4;        // strip this thread loads (tid<240)
    const int kk   = tid & 15;        // row-quad within strip

    // ---- one-time init ----
    for (int idx = tid; idx < SCOL * 44; idx += 256) {        // W strip -> LDS
        int j = idx / 44, ch = idx % 44;
        *(uint4*)(W_s + j * WSTR + ch * 8) =
            *(const uint4*)(Wswz + (size_t)s * SCOL * NKPAD + j * NKPAD + ch * 8);
    }
    for (int idx = tid; idx < BB * NH; idx += 256) {          // zero h region
        int row = idx / NH, k = idx % NH;
        A_s[row * ASTR + k] = 0;
    }
    for (int idx = tid; idx < BB * 26; idx += 256) {          // zero pad 350..375
        int row = idx / 26, k = 350 + idx % 26;
        A_s[row * ASTR + k] = 0;
    }
    for (int idx = tid; idx < BB * HS; idx += 256) c_s[idx] = 0.f;
    for (int idx = tid; idx < NH * NC; idx += 256) U_s[idx] = U[idx];
    if (tid < SCOL) b_s[tid] = bias[(tid & 3) * NH + s * HS + (tid >> 2)];
    float b2r[5];
#pragma unroll
    for (int c = 0; c < 5; ++c) b2r[c] = b2[c];
    load_x(tokens, emb, b0, 0, A_s, tid);
    __syncthreads();

    const unsigned short* Ab = A_s + (wave * 16 + c15) * ASTR + kq * 8;
    const unsigned short* Wb = W_s + c15 * WSTR + kq * 8;

    for (int t = 0; t < NT; ++t) {
        // ---- 1) K-loop: z-strip = A(64x352) @ Wstrip(352x80) ----
        f32x4 acc[5];
#pragma unroll
        for (int n = 0; n < 5; ++n) acc[n] = (f32x4){0.f, 0.f, 0.f, 0.f};
#pragma unroll
        for (int ks = 0; ks < 11; ++ks) {
            short8 av = *(const short8*)(Ab + ks * 32);
#pragma unroll
            for (int n = 0; n < 5; ++n) {
                short8 bv = *(const short8*)(Wb + n * 16 * WSTR + ks * 32);
                acc[n] = __builtin_amdgcn_mfma_f32_16x16x32_bf16(av, bv, acc[n], 0, 0, 0);
            }
        }
#pragma unroll
        for (int n = 0; n < 5; ++n)
#pragma unroll
            for (int j = 0; j < 4; ++j)
                z_s[(wave * 16 + kq * 4 + j) * ZSTR + n * 16 + c15] = acc[n][j];
        __syncthreads();

        // ---- 2) x gather t+1 (latency hides under cell) + cell update ----
        if (t + 1 < NT) load_x(tokens, emb, b0, t + 1, A_s, tid);
#pragma unroll
        for (int ii = 0; ii < 5; ++ii) {
            int idx = tid * 5 + ii;
            int row = idx / HS, h = idx % HS;
            f32x4 z4 = *(f32x4*)(z_s + row * ZSTR + h * 4);
            float zi = z4[0] + b_s[4 * h + 0];
            float zj = z4[1] + b_s[4 * h + 1];
            float zf = z4[2] + b_s[4 * h + 2];
            float zo = z4[3] + b_s[4 * h + 3];
            float co = c_s[idx];
            float fg = sigmoid_fast(zf + 1.f);   // forget bias 1.0
            float ig = sigmoid_fast(zi);
            float og = sigmoid_fast(zo);
            float cn = fg * co + ig * tanh_fast(zj);
            float hn = og * tanh_fast(cn);
            c_s[idx] = cn;
            h_stage[idx] = f2bf(hn);
        }
        __syncthreads();

        // ---- 3) h store issue; CE phase0 (LDS-only) covers store flight ----
        unsigned short* hb = hbuf + (size_t)(t & 1) * (NBATCH * HBSTR);
        store_h(hb, b0, s, h_stage, tid);
        ce_phase0(t >= 1, r0, nr, A_s, U_s, llds, tid);
        asm volatile("s_waitcnt vmcnt(0)" ::: "memory");
        __syncthreads();

        // ---- 4) flag raise + merged per-strip {poll -> load} ----
        if (tid == 0)
            __hip_atomic_store(flags + (size_t)(t * NGRP + g) * 16 + s, 1,
                               __ATOMIC_RELAXED, __HIP_MEMORY_SCOPE_AGENT);
        if (tid < 240) {
            if (sp == s) {
                // own strip: LDS->LDS copy from h_stage (no MALL trip)
#pragma unroll
                for (int r4 = 0; r4 < 4; ++r4) {
                    int row = kk * 4 + r4;
#pragma unroll
                    for (int j = 0; j < 5; ++j)
                        *(ull*)(A_s + row * ASTR + s * HS + j * 4) =
                            *(const ull*)(h_stage + row * HS + j * 4);
                }
            } else {
                // wave-leader for this strip polls; broadcast via shuffle
                const int lead = lane & ~15;
                const int* fp = flags + (size_t)(t * NGRP + g) * 16 + sp;
                int fv = 0; int gu = 0;
                do {
                    int lv = 0;
                    if (lane == lead)
                        lv = __hip_atomic_load(fp, __ATOMIC_RELAXED,
                                               __HIP_MEMORY_SCOPE_AGENT);
                    fv = __shfl(lv, lead, 64);
                    if (!fv) __builtin_amdgcn_s_sleep(2);
                } while (!fv && ++gu < (1 << 20));
                // load this strip's 4 rows x 5 chunks (pipelined)
                ull v[20];
#pragma unroll
                for (int r4 = 0; r4 < 4; ++r4)
#pragma unroll
                    for (int j = 0; j < 5; ++j)
                        v[r4 * 5 + j] = __hip_atomic_load(
                            (const ull*)(hb + (size_t)(b0 + kk * 4 + r4) * HBSTR
                                         + sp * HS + j * 4),
                            __ATOMIC_RELAXED, __HIP_MEMORY_SCOPE_AGENT);
#pragma unroll
                for (int r4 = 0; r4 < 4; ++r4)
#pragma unroll
                    for (int j = 0; j < 5; ++j)
                        *(ull*)(A_s + (kk * 4 + r4) * ASTR + sp * HS + j * 4) =
                            v[r4 * 5 + j];
            }
        } else {
            // threads 240..255: CE epilogue (reads only llds)
            ce_final(t >= 1, t - 1, b0, r0, nr, b2r, labels, mask,
                     ce_arr, llds, tid - 240);
        }
        __syncthreads();
    }

    // ---- CE for final step (h_119 in A_s) ----
    ce_phase0(true, r0, nr, A_s, U_s, llds, tid);
    __syncthreads();
    ce_final(true, NT - 1, b0, r0, nr, b2r, labels, mask, ce_arr, llds, tid);
}

// ---------------------------------------------------------------------------
// Deterministic two-stage reduction: sum(ce) / sum(mask).
// ---------------------------------------------------------------------------
__global__ __launch_bounds__(256)
void reduce1_kernel(const float* __restrict__ ce_arr,
                    const int* __restrict__ mask,
                    float* __restrict__ pce, float* __restrict__ pm)
{
    __shared__ float s_ce[256];
    __shared__ float s_m[256];
    const int tid = threadIdx.x;
    const int lo = blockIdx.x * 480;     // 122880 / 256
    float ac = 0.f, am = 0.f;
    for (int i = lo + tid; i < lo + 480; i += 256) {
        ac += ce_arr[i];
        am += (float)mask[i];
    }
    s_ce[tid] = ac; s_m[tid] = am;
    __syncthreads();
    for (int r = 128; r > 0; r >>= 1) {
        if (tid < r) { s_ce[tid] += s_ce[tid + r]; s_m[tid] += s_m[tid + r]; }
        __syncthreads();
    }
    if (tid == 0) { pce[blockIdx.x] = s_ce[0]; pm[blockIdx.x] = s_m[0]; }
}

__global__ __launch_bounds__(256)
void reduce2_kernel(const float* __restrict__ pce,
                    const float* __restrict__ pm,
                    float* __restrict__ out)
{
    __shared__ float s_ce[256];
    __shared__ float s_m[256];
    const int tid = threadIdx.x;
    s_ce[tid] = pce[tid];
    s_m[tid]  = pm[tid];
    __syncthreads();
    for (int r = 128; r > 0; r >>= 1) {
        if (tid < r) { s_ce[tid] += s_ce[tid + r]; s_m[tid] += s_m[tid + r]; }
        __syncthreads();
    }
    if (tid == 0) out[0] = s_ce[0] / s_m[0];
}

// ---------------------------------------------------------------------------
extern "C" void kernel_launch(void* const* d_in, const int* in_sizes, int n_in,
                              void* d_out, int out_size, void* d_ws, size_t ws_size,
                              hipStream_t stream)
{
    const int*   tokens = (const int*)d_in[0];
    const int*   labels = (const int*)d_in[1];
    const int*   mask   = (const int*)d_in[2];
    const float* emb    = (const float*)d_in[3];
    const float* Wx     = (const float*)d_in[4];
    const float* Wh     = (const float*)d_in[5];
    const float* bias   = (const float*)d_in[6];
    const float* U      = (const float*)d_in[7];
    const float* b2     = (const float*)d_in[8];

    char* wsb = (char*)d_ws;
    unsigned short* Wswz = (unsigned short*)wsb;                      // 844800 B
    unsigned short* hbuf = (unsigned short*)(wsb + 844800);           // 1245184 B
    float* ce    = (float*)(wsb + 2089984);                           // 491520 B
    float* pce   = (float*)(wsb + 2581504);                           // 1024 B
    float* pm    = (float*)(wsb + 2582528);                           // 1024 B
    int*   flags = (int*)(wsb + 2583552);                             // 122880 B

    hipMemsetAsync(flags, 0, 122880, stream);
    wswz_kernel<<<(NSTRIP * SCOL * NKPAD + 255) / 256, 256, 0, stream>>>(Wx, Wh, Wswz);
    lstm_persist<<<NGRP * NSTRIP, 256, 0, stream>>>(
        tokens, labels, mask, emb, bias, U, b2, Wswz, hbuf, ce, flags);
    reduce1_kernel<<<256, 256, 0, stream>>>(ce, mask, pce, pm);
    reduce2_kernel<<<1, 256, 0, stream>>>(pce, pm, (float*)d_out);
}

// Round 13
// 684.523 us; speedup vs baseline: 1.7353x; 1.3159x over previous
//
#include <hip/hip_runtime.h>
#include <hip/hip_bf16.h>
#include <math.h>

#define NBATCH 1024
#define NT 120
#define NE 50
#define NH 300
#define NC 5
#define GH 1200
#define NKPAD 352      // K = NH + NE padded to 352
#define NSTRIP 15      // hidx strips of 20
#define HS 20          // hidx per strip
#define SCOL 80        // strip cols = 4*HS (gates interleaved: col = 4*hsub+g)
#define NGRP 16        // batch groups
#define BB 64          // batch rows per group
#define ASTR 376       // A_lds row stride in ushorts
#define WSTR 376
#define ZSTR 84        // z_lds row stride in floats (16B-aligned float4 reads)
#define HBSTR 304      // hbuf row stride in ushorts (608B rows)
#define HCH 76         // 8B chunks per hbuf row
#define NCHUNK 4800    // 64 rows x 75 x 8B chunks of live h data

typedef __attribute__((ext_vector_type(8))) short short8;
typedef __attribute__((ext_vector_type(4))) float f32x4;
typedef __attribute__((ext_vector_type(2))) unsigned short us2;

static __device__ __forceinline__ float bf2f(unsigned short u) {
    unsigned int x = ((unsigned int)u) << 16;
    return __builtin_bit_cast(float, x);
}
static __device__ __forceinline__ unsigned short f2bf(float f) {
    __hip_bfloat16 h = __float2bfloat16(f);   // RNE
    return __builtin_bit_cast(unsigned short, h);
}

// Fast device transcendentals: v_exp_f32 / v_rcp_f32 (~1 ulp, 4-cyc issue).
static __device__ __forceinline__ float sigmoid_fast(float x) {
    return __builtin_amdgcn_rcpf(1.f + __expf(-x));
}
static __device__ __forceinline__ float tanh_fast(float x) {
    return 1.f - 2.f * __builtin_amdgcn_rcpf(1.f + __expf(2.f * x));
}

// ---------------------------------------------------------------------------
// Prepass: swizzle [Wh;Wx] into strip-major bf16: Wswz[s][j][k], j=4*hsub+g,
// k: 0..299 = Wh rows, 300..349 = Wx rows, 350..351 = 0.
// ---------------------------------------------------------------------------
__global__ __launch_bounds__(256)
void wswz_kernel(const float* __restrict__ Wx, const float* __restrict__ Wh,
                 unsigned short* __restrict__ Wswz)
{
    int idx = blockIdx.x * 256 + threadIdx.x;
    if (idx >= NSTRIP * SCOL * NKPAD) return;
    int s = idx / (SCOL * NKPAD);
    int r = idx % (SCOL * NKPAD);
    int j = r / NKPAD, k = r % NKPAD;
    int col = (j & 3) * NH + s * HS + (j >> 2);
    float v = 0.f;
    if (k < NH)           v = Wh[k * GH + col];
    else if (k < NH + NE) v = Wx[(k - NH) * GH + col];
    Wswz[idx] = f2bf(v);
}

// ---------------------------------------------------------------------------
// h slab load (PROVEN r3/r5 path): agent-scope relaxed 8B loads, 19 in flight.
// ---------------------------------------------------------------------------
__device__ __forceinline__ void load_h(const unsigned short* __restrict__ hb,
                                       int b0, unsigned short* A_s, int tid)
{
    const unsigned long long* src =
        (const unsigned long long*)(hb + (size_t)b0 * HBSTR);
    unsigned long long v[19];
#pragma unroll
    for (int m = 0; m < 19; ++m) {
        const int idx = tid + 256 * m;
        if (idx < NCHUNK) {
            const int row = idx / 75, j = idx % 75;
            v[m] = __hip_atomic_load(src + (size_t)row * HCH + j,
                                     __ATOMIC_RELAXED, __HIP_MEMORY_SCOPE_AGENT);
        }
    }
#pragma unroll
    for (int m = 0; m < 19; ++m) {
        const int idx = tid + 256 * m;
        if (idx < NCHUNK) {
            const int row = idx / 75, j = idx % 75;
            *(unsigned long long*)(A_s + row * ASTR + j * 4) = v[m];
        }
    }
}

// h strip store: 320 coalesced 8B agent-scope stores from the LDS stage.
__device__ __forceinline__ void store_h(unsigned short* hb, int b0, int st,
                                        const unsigned short* h_stage, int tid)
{
#pragma unroll
    for (int m = 0; m < 2; ++m) {
        const int c = tid + m * 256;
        if (c < 320) {
            const int row = c / 5, j = c % 5;
            unsigned long long val =
                *(const unsigned long long*)(h_stage + row * HS + j * 4);
            unsigned long long* p = (unsigned long long*)
                (hb + (size_t)(b0 + row) * HBSTR + st * HS + j * 4);
            __hip_atomic_store(p, val, __ATOMIC_RELAXED,
                               __HIP_MEMORY_SCOPE_AGENT);
        }
    }
}

__device__ __forceinline__ void load_x(const int* __restrict__ tokens,
                                       const float* __restrict__ emb,
                                       int b0, int t, unsigned short* A_s, int tid)
{
    const int row = tid >> 2, q = tid & 3;
    const int tok = tokens[(b0 + row) * NT + t];
    const float* er = emb + (size_t)tok * NE;
    unsigned short* dst = A_s + row * ASTR + NH;   // x at k=300..349
    for (int m = 0; m < 7; ++m) {
        int f = q + 4 * m;                  // float2 index 0..24
        if (f < 25) {
            float2 v = *(const float2*)(er + f * 2);
            us2 o; o.x = f2bf(v.x); o.y = f2bf(v.y);
            *(us2*)(dst + f * 2) = o;
        }
    }
}

__device__ __forceinline__ void do_ce(bool doCE, int tc, int b0, int r0, int nr,
        const unsigned short* A_s, const float* U_s, const float* __restrict__ b2,
        const int* __restrict__ labels, const int* __restrict__ mask,
        float* __restrict__ ce_arr, float* llds, float* lgl, int tid)
{
    if (doCE && tid < nr * 50) {
        int i = tid / 50, rem = tid % 50, c = rem / 10, q = rem % 10;
        const unsigned short* ar = A_s + (r0 + i) * ASTR + q * 30;
        const float* up = U_s + q * 30 * NC + c;
        float acc = 0.f;
#pragma unroll
        for (int k2 = 0; k2 < 15; ++k2) {     // us2 reads, same k order
            us2 hv = *(const us2*)(ar + k2 * 2);
            acc += bf2f(hv.x) * up[(k2 * 2) * NC];
            acc += bf2f(hv.y) * up[(k2 * 2 + 1) * NC];
        }
        llds[i * 50 + c * 10 + q] = acc;
    }
    __syncthreads();
    if (doCE && tid < nr * NC) {
        int i = tid / NC, c = tid % NC;
        const float* pp = llds + i * 50 + c * 10;
        float sum = pp[0]+pp[1]+pp[2]+pp[3]+pp[4]+pp[5]+pp[6]+pp[7]+pp[8]+pp[9];
        lgl[i * NC + c] = sum + b2[c];
    }
    __syncthreads();
    if (doCE && tid < nr) {
        const float* L = lgl + tid * NC;
        float m = fmaxf(fmaxf(fmaxf(L[0], L[1]), fmaxf(L[2], L[3])), L[4]);
        float ssum = expf(L[0]-m)+expf(L[1]-m)+expf(L[2]-m)+expf(L[3]-m)+expf(L[4]-m);
        float lse = m + logf(ssum);
        int bidx = b0 + r0 + tid;
        int lab = labels[bidx * NT + tc];
        int mk  = mask[bidx * NT + tc];
        ce_arr[bidx * NT + tc] = mk ? (lse - L[lab]) : 0.f;
    }
}

// ---------------------------------------------------------------------------
// Persistent LSTM kernel: 240 blocks = 16 batch-groups x 15 strips.
// r8 structure exactly; data-path micro-opts only.
// ---------------------------------------------------------------------------
__global__ __launch_bounds__(256, 1)
void lstm_persist(const int* __restrict__ tokens,
                  const int* __restrict__ labels,
                  const int* __restrict__ mask,
                  const float* __restrict__ emb,
                  const float* __restrict__ bias,
                  const float* __restrict__ U,
                  const float* __restrict__ b2,
                  const unsigned short* __restrict__ Wswz,
                  unsigned short* __restrict__ hbuf,
                  float* __restrict__ ce_arr,
                  int* __restrict__ flags)
{
    __shared__ unsigned short A_s[BB * ASTR];     // [h(0..299) | x(300..349) | 0]
    __shared__ unsigned short W_s[SCOL * WSTR];
    __shared__ __align__(16) unsigned short h_stage[BB * HS];
    __shared__ float z_s[BB * ZSTR];
    __shared__ float c_s[BB * HS];
    __shared__ float U_s[NH * NC];
    __shared__ float b_s[SCOL];
    __shared__ float llds[5 * 50];
    __shared__ float lgl[32];

    const int tid  = threadIdx.x;
    const int g    = blockIdx.x & 15;
    const int s    = blockIdx.x >> 4;
    const int b0   = g * BB;
    const int wave = tid >> 6;
    const int lane = tid & 63;
    const int c15  = lane & 15;
    const int kq   = lane >> 4;
    const int r0   = (s * BB) / NSTRIP;
    const int r1   = ((s + 1) * BB) / NSTRIP;
    const int nr   = r1 - r0;

    // ---- one-time init ----
    for (int idx = tid; idx < SCOL * 44; idx += 256) {        // W strip -> LDS
        int j = idx / 44, ch = idx % 44;
        *(uint4*)(W_s + j * WSTR + ch * 8) =
            *(const uint4*)(Wswz + (size_t)s * SCOL * NKPAD + j * NKPAD + ch * 8);
    }
    for (int idx = tid; idx < BB * NH; idx += 256) {          // zero h region
        int row = idx / NH, k = idx % NH;
        A_s[row * ASTR + k] = 0;
    }
    for (int idx = tid; idx < BB * 26; idx += 256) {          // zero pad 350..375
        int row = idx / 26, k = 350 + idx % 26;
        A_s[row * ASTR + k] = 0;
    }
    for (int idx = tid; idx < BB * HS; idx += 256) c_s[idx] = 0.f;
    for (int idx = tid; idx < NH * NC; idx += 256) U_s[idx] = U[idx];
    if (tid < SCOL) b_s[tid] = bias[(tid & 3) * NH + s * HS + (tid >> 2)];
    load_x(tokens, emb, b0, 0, A_s, tid);
    __syncthreads();

    // bias -> registers (loop-invariant: thread's 5 h-values are fixed)
    float bz[20];
    {
        const int hbase4 = 4 * ((5 * tid) % 20);
#pragma unroll
        for (int j = 0; j < 20; ++j) bz[j] = b_s[hbase4 + j];
    }

    const unsigned short* Ab = A_s + (wave * 16 + c15) * ASTR + kq * 8;
    const unsigned short* Wb = W_s + c15 * WSTR + kq * 8;

    for (int t = 0; t < NT; ++t) {
        // ---- 1) K-loop: z-strip = A(64x352) @ Wstrip(352x80) ----
        f32x4 acc[5];
#pragma unroll
        for (int n = 0; n < 5; ++n) acc[n] = (f32x4){0.f, 0.f, 0.f, 0.f};
#pragma unroll
        for (int ks = 0; ks < 11; ++ks) {
            short8 av = *(const short8*)(Ab + ks * 32);
#pragma unroll
            for (int n = 0; n < 5; ++n) {
                short8 bv = *(const short8*)(Wb + n * 16 * WSTR + ks * 32);
                acc[n] = __builtin_amdgcn_mfma_f32_16x16x32_bf16(av, bv, acc[n], 0, 0, 0);
            }
        }
#pragma unroll
        for (int n = 0; n < 5; ++n)
#pragma unroll
            for (int j = 0; j < 4; ++j)
                z_s[(wave * 16 + kq * 4 + j) * ZSTR + n * 16 + c15] = acc[n][j];
        __syncthreads();

        // ---- 2) x gather t+1 (latency hides under cell) + cell update ----
        if (t + 1 < NT) load_x(tokens, emb, b0, t + 1, A_s, tid);
#pragma unroll
        for (int ii = 0; ii < 5; ++ii) {
            int idx = tid * 5 + ii;
            int row = idx / HS, h = idx % HS;
            f32x4 z4 = *(f32x4*)(z_s + row * ZSTR + h * 4);
            float zi = z4[0] + bz[ii * 4 + 0];
            float zj = z4[1] + bz[ii * 4 + 1];
            float zf = z4[2] + bz[ii * 4 + 2];
            float zo = z4[3] + bz[ii * 4 + 3];
            float co = c_s[idx];
            float fg = sigmoid_fast(zf + 1.f);   // forget bias 1.0
            float ig = sigmoid_fast(zi);
            float og = sigmoid_fast(zo);
            float cn = fg * co + ig * tanh_fast(zj);
            float hn = og * tanh_fast(cn);
            c_s[idx] = cn;
            h_stage[idx] = f2bf(hn);
        }
        __syncthreads();

        // ---- 3) coalesced 8B h strip store + drain ----
        unsigned short* hb = hbuf + (size_t)(t & 1) * (NBATCH * HBSTR);
        store_h(hb, b0, s, h_stage, tid);
        asm volatile("s_waitcnt vmcnt(0)" ::: "memory");
        __syncthreads();

        // ---- 4) raise per-strip flag + pre-issue first flag probe ----
        if (tid == 0)
            __hip_atomic_store(flags + (size_t)(t * NGRP + g) * 16 + s, 1,
                               __ATOMIC_RELAXED, __HIP_MEMORY_SCOPE_AGENT);
        const int* fp = flags + (size_t)(t * NGRP + g) * 16 + tid;
        int fv0 = 1;
        if (tid < NSTRIP)
            fv0 = __hip_atomic_load(fp, __ATOMIC_RELAXED,
                                    __HIP_MEMORY_SCOPE_AGENT);

        // ---- 5) overlap window: CE(t-1) while flags + probe fly ----
        do_ce(t >= 1, t - 1, b0, r0, nr, A_s, U_s, b2, labels, mask,
              ce_arr, llds, lgl, tid);

        // ---- 6) fallback poll only if the probe missed ----
        if (tid < NSTRIP && !fv0) {
            int fv = 0; int gu = 0;
            do {
                fv = __hip_atomic_load(fp, __ATOMIC_RELAXED,
                                       __HIP_MEMORY_SCOPE_AGENT);
                if (!fv) __builtin_amdgcn_s_sleep(1);
            } while (!fv && ++gu < (1 << 17));
        }
        __syncthreads();

        // ---- 7) pull group h slab into A_s ----
        load_h(hb, b0, A_s, tid);
        __syncthreads();
    }

    // ---- CE for final step (h_119 in A_s) ----
    do_ce(true, NT - 1, b0, r0, nr, A_s, U_s, b2, labels, mask,
          ce_arr, llds, lgl, tid);
}

// ---------------------------------------------------------------------------
// Deterministic two-stage reduction: sum(ce) / sum(mask).
// ---------------------------------------------------------------------------
__global__ __launch_bounds__(256)
void reduce1_kernel(const float* __restrict__ ce_arr,
                    const int* __restrict__ mask,
                    float* __restrict__ pce, float* __restrict__ pm)
{
    __shared__ float s_ce[256];
    __shared__ float s_m[256];
    const int tid = threadIdx.x;
    const int lo = blockIdx.x * 480;     // 122880 / 256
    float ac = 0.f, am = 0.f;
    for (int i = lo + tid; i < lo + 480; i += 256) {
        ac += ce_arr[i];
        am += (float)mask[i];
    }
    s_ce[tid] = ac; s_m[tid] = am;
    __syncthreads();
    for (int r = 128; r > 0; r >>= 1) {
        if (tid < r) { s_ce[tid] += s_ce[tid + r]; s_m[tid] += s_m[tid + r]; }
        __syncthreads();
    }
    if (tid == 0) { pce[blockIdx.x] = s_ce[0]; pm[blockIdx.x] = s_m[0]; }
}

__global__ __launch_bounds__(256)
void reduce2_kernel(const float* __restrict__ pce,
                    const float* __restrict__ pm,
                    float* __restrict__ out)
{
    __shared__ float s_ce[256];
    __shared__ float s_m[256];
    const int tid = threadIdx.x;
    s_ce[tid] = pce[tid];
    s_m[tid]  = pm[tid];
    __syncthreads();
    for (int r = 128; r > 0; r >>= 1) {
        if (tid < r) { s_ce[tid] += s_ce[tid + r]; s_m[tid] += s_m[tid + r]; }
        __syncthreads();
    }
    if (tid == 0) out[0] = s_ce[0] / s_m[0];
}

// ---------------------------------------------------------------------------
extern "C" void kernel_launch(void* const* d_in, const int* in_sizes, int n_in,
                              void* d_out, int out_size, void* d_ws, size_t ws_size,
                              hipStream_t stream)
{
    const int*   tokens = (const int*)d_in[0];
    const int*   labels = (const int*)d_in[1];
    const int*   mask   = (const int*)d_in[2];
    const float* emb    = (const float*)d_in[3];
    const float* Wx     = (const float*)d_in[4];
    const float* Wh     = (const float*)d_in[5];
    const float* bias   = (const float*)d_in[6];
    const float* U      = (const float*)d_in[7];
    const float* b2     = (const float*)d_in[8];

    char* wsb = (char*)d_ws;
    unsigned short* Wswz = (unsigned short*)wsb;                      // 844800 B
    unsigned short* hbuf = (unsigned short*)(wsb + 844800);           // 1245184 B
    float* ce    = (float*)(wsb + 2089984);                           // 491520 B
    float* pce   = (float*)(wsb + 2581504);                           // 1024 B
    float* pm    = (float*)(wsb + 2582528);                           // 1024 B
    int*   flags = (int*)(wsb + 2583552);                             // 122880 B

    (void)hipMemsetAsync(flags, 0, 122880, stream);
    wswz_kernel<<<(NSTRIP * SCOL * NKPAD + 255) / 256, 256, 0, stream>>>(Wx, Wh, Wswz);
    lstm_persist<<<NGRP * NSTRIP, 256, 0, stream>>>(
        tokens, labels, mask, emb, bias, U, b2, Wswz, hbuf, ce, flags);
    reduce1_kernel<<<256, 256, 0, stream>>>(ce, mask, pce, pm);
    reduce2_kernel<<<1, 256, 0, stream>>>(pce, pm, (float*)d_out);
}

// Round 14
// 643.082 us; speedup vs baseline: 1.8472x; 1.0644x over previous
//
#include <hip/hip_runtime.h>
#include <hip/hip_bf16.h>
#include <math.h>

#define NBATCH 1024
#define NT 120
#define NE 50
#define NH 300
#define NC 5
#define GH 1200
#define NKPAD 352      // K = NH + NE padded to 352
#define NSTRIP 15      // hidx strips of 20
#define HS 20          // hidx per strip
#define SCOL 80        // strip cols = 4*HS (gates interleaved: col = 4*hsub+g)
#define NGRP 16        // batch groups
#define BB 64          // batch rows per group
#define ASTR 376       // A_lds row stride in ushorts (752B = 47*16B, odd -> spread)
#define WSTR 376
#define ZSTR 84        // z_lds row stride in floats (16B-aligned float4 reads)
#define HBSTR 304      // hbuf row stride in ushorts (608B rows)
#define HCH 76         // 8B chunks per hbuf row
#define NCHUNK 4800    // 64 rows x 75 x 8B chunks of live h data

typedef __attribute__((ext_vector_type(8))) short short8;
typedef __attribute__((ext_vector_type(4))) float f32x4;
typedef __attribute__((ext_vector_type(2))) unsigned short us2;

static __device__ __forceinline__ float bf2f(unsigned short u) {
    unsigned int x = ((unsigned int)u) << 16;
    return __builtin_bit_cast(float, x);
}
static __device__ __forceinline__ unsigned short f2bf(float f) {
    __hip_bfloat16 h = __float2bfloat16(f);   // RNE
    return __builtin_bit_cast(unsigned short, h);
}

// Fast device transcendentals: v_exp_f32 / v_rcp_f32 (~1 ulp, 4-cyc issue).
static __device__ __forceinline__ float sigmoid_fast(float x) {
    return __builtin_amdgcn_rcpf(1.f + __expf(-x));
}
static __device__ __forceinline__ float tanh_fast(float x) {
    return 1.f - 2.f * __builtin_amdgcn_rcpf(1.f + __expf(2.f * x));
}

// ---------------------------------------------------------------------------
// Prepass: swizzle [Wh;Wx] into strip-major bf16: Wswz[s][j][k], j=4*hsub+g,
// k: 0..299 = Wh rows, 300..349 = Wx rows, 350..351 = 0.
// ---------------------------------------------------------------------------
__global__ __launch_bounds__(256)
void wswz_kernel(const float* __restrict__ Wx, const float* __restrict__ Wh,
                 unsigned short* __restrict__ Wswz)
{
    int idx = blockIdx.x * 256 + threadIdx.x;
    if (idx >= NSTRIP * SCOL * NKPAD) return;
    int s = idx / (SCOL * NKPAD);
    int r = idx % (SCOL * NKPAD);
    int j = r / NKPAD, k = r % NKPAD;
    int col = (j & 3) * NH + s * HS + (j >> 2);
    float v = 0.f;
    if (k < NH)           v = Wh[k * GH + col];
    else if (k < NH + NE) v = Wx[(k - NH) * GH + col];
    Wswz[idx] = f2bf(v);
}

// ---------------------------------------------------------------------------
// h slab load (PROVEN r3/r5 path): agent-scope relaxed 8B loads, 19 in flight.
// ---------------------------------------------------------------------------
__device__ __forceinline__ void load_h(const unsigned short* __restrict__ hb,
                                       int b0, unsigned short* A_s, int tid)
{
    const unsigned long long* src =
        (const unsigned long long*)(hb + (size_t)b0 * HBSTR);
    unsigned long long v[19];
#pragma unroll
    for (int m = 0; m < 19; ++m) {
        const int idx = tid + 256 * m;
        if (idx < NCHUNK) {
            const int row = idx / 75, j = idx % 75;
            v[m] = __hip_atomic_load(src + (size_t)row * HCH + j,
                                     __ATOMIC_RELAXED, __HIP_MEMORY_SCOPE_AGENT);
        }
    }
#pragma unroll
    for (int m = 0; m < 19; ++m) {
        const int idx = tid + 256 * m;
        if (idx < NCHUNK) {
            const int row = idx / 75, j = idx % 75;
            *(unsigned long long*)(A_s + row * ASTR + j * 4) = v[m];
        }
    }
}

// h strip store: 320 coalesced 8B agent-scope stores from the LDS stage.
__device__ __forceinline__ void store_h(unsigned short* hb, int b0, int st,
                                        const unsigned short* h_stage, int tid)
{
#pragma unroll
    for (int m = 0; m < 2; ++m) {
        const int c = tid + m * 256;
        if (c < 320) {
            const int row = c / 5, j = c % 5;
            unsigned long long val =
                *(const unsigned long long*)(h_stage + row * HS + j * 4);
            unsigned long long* p = (unsigned long long*)
                (hb + (size_t)(b0 + row) * HBSTR + st * HS + j * 4);
            __hip_atomic_store(p, val, __ATOMIC_RELAXED,
                               __HIP_MEMORY_SCOPE_AGENT);
        }
    }
}

__device__ __forceinline__ void load_x(const int* __restrict__ tokens,
                                       const float* __restrict__ emb,
                                       int b0, int t, unsigned short* A_s, int tid)
{
    const int row = tid >> 2, q = tid & 3;
    const int tok = tokens[(b0 + row) * NT + t];
    const float* er = emb + (size_t)tok * NE;
    unsigned short* dst = A_s + row * ASTR + NH;   // x at k=300..349
    for (int m = 0; m < 7; ++m) {
        int f = q + 4 * m;                  // float2 index 0..24
        if (f < 25) {
            float2 v = *(const float2*)(er + f * 2);
            us2 o; o.x = f2bf(v.x); o.y = f2bf(v.y);
            *(us2*)(dst + f * 2) = o;
        }
    }
}

__device__ __forceinline__ void do_ce(bool doCE, int tc, int b0, int r0, int nr,
        const unsigned short* A_s, const float* U_s, const float* __restrict__ b2,
        const int* __restrict__ labels, const int* __restrict__ mask,
        float* __restrict__ ce_arr, float* llds, float* lgl, int tid)
{
    if (doCE && tid < nr * 50) {
        int i = tid / 50, rem = tid % 50, c = rem / 10, q = rem % 10;
        const unsigned short* ar = A_s + (r0 + i) * ASTR + q * 30;
        const float* up = U_s + q * 30 * NC + c;
        float acc = 0.f;
#pragma unroll
        for (int k = 0; k < 30; ++k) acc += bf2f(ar[k]) * up[k * NC];
        llds[i * 50 + c * 10 + q] = acc;
    }
    __syncthreads();
    if (doCE && tid < nr * NC) {
        int i = tid / NC, c = tid % NC;
        const float* pp = llds + i * 50 + c * 10;
        float sum = pp[0]+pp[1]+pp[2]+pp[3]+pp[4]+pp[5]+pp[6]+pp[7]+pp[8]+pp[9];
        lgl[i * NC + c] = sum + b2[c];
    }
    __syncthreads();
    if (doCE && tid < nr) {
        const float* L = lgl + tid * NC;
        float m = fmaxf(fmaxf(fmaxf(L[0], L[1]), fmaxf(L[2], L[3])), L[4]);
        float ssum = expf(L[0]-m)+expf(L[1]-m)+expf(L[2]-m)+expf(L[3]-m)+expf(L[4]-m);
        float lse = m + logf(ssum);
        int bidx = b0 + r0 + tid;
        int lab = labels[bidx * NT + tc];
        int mk  = mask[bidx * NT + tc];
        ce_arr[bidx * NT + tc] = mk ? (lse - L[lab]) : 0.f;
    }
}

// ---------------------------------------------------------------------------
// Persistent LSTM kernel: 240 blocks = 16 batch-groups x 15 strips.
// r5 structure (W strip in LDS); fast cell math; hoisted x gather.
// ---------------------------------------------------------------------------
__global__ __launch_bounds__(256, 1)
void lstm_persist(const int* __restrict__ tokens,
                  const int* __restrict__ labels,
                  const int* __restrict__ mask,
                  const float* __restrict__ emb,
                  const float* __restrict__ bias,
                  const float* __restrict__ U,
                  const float* __restrict__ b2,
                  const unsigned short* __restrict__ Wswz,
                  unsigned short* __restrict__ hbuf,
                  float* __restrict__ ce_arr,
                  int* __restrict__ flags)
{
    __shared__ unsigned short A_s[BB * ASTR];     // [h(0..299) | x(300..349) | 0]
    __shared__ unsigned short W_s[SCOL * WSTR];
    __shared__ __align__(16) unsigned short h_stage[BB * HS];
    __shared__ float z_s[BB * ZSTR];
    __shared__ float c_s[BB * HS];
    __shared__ float U_s[NH * NC];
    __shared__ float b_s[SCOL];
    __shared__ float llds[5 * 50];
    __shared__ float lgl[32];

    const int tid  = threadIdx.x;
    const int g    = blockIdx.x & 15;
    const int s    = blockIdx.x >> 4;
    const int b0   = g * BB;
    const int wave = tid >> 6;
    const int lane = tid & 63;
    const int c15  = lane & 15;
    const int kq   = lane >> 4;
    const int r0   = (s * BB) / NSTRIP;
    const int r1   = ((s + 1) * BB) / NSTRIP;
    const int nr   = r1 - r0;

    // ---- one-time init ----
    for (int idx = tid; idx < SCOL * 44; idx += 256) {        // W strip -> LDS
        int j = idx / 44, ch = idx % 44;
        *(uint4*)(W_s + j * WSTR + ch * 8) =
            *(const uint4*)(Wswz + (size_t)s * SCOL * NKPAD + j * NKPAD + ch * 8);
    }
    for (int idx = tid; idx < BB * NH; idx += 256) {          // zero h region
        int row = idx / NH, k = idx % NH;
        A_s[row * ASTR + k] = 0;
    }
    for (int idx = tid; idx < BB * 26; idx += 256) {          // zero pad 350..375
        int row = idx / 26, k = 350 + idx % 26;
        A_s[row * ASTR + k] = 0;
    }
    for (int idx = tid; idx < BB * HS; idx += 256) c_s[idx] = 0.f;
    for (int idx = tid; idx < NH * NC; idx += 256) U_s[idx] = U[idx];
    if (tid < SCOL) b_s[tid] = bias[(tid & 3) * NH + s * HS + (tid >> 2)];
    load_x(tokens, emb, b0, 0, A_s, tid);
    __syncthreads();

    const unsigned short* Ab = A_s + (wave * 16 + c15) * ASTR + kq * 8;
    const unsigned short* Wb = W_s + c15 * WSTR + kq * 8;

    for (int t = 0; t < NT; ++t) {
        // ---- 1) K-loop: z-strip = A(64x352) @ Wstrip(352x80) ----
        f32x4 acc[5];
#pragma unroll
        for (int n = 0; n < 5; ++n) acc[n] = (f32x4){0.f, 0.f, 0.f, 0.f};
#pragma unroll
        for (int ks = 0; ks < 11; ++ks) {
            short8 av = *(const short8*)(Ab + ks * 32);
#pragma unroll
            for (int n = 0; n < 5; ++n) {
                short8 bv = *(const short8*)(Wb + n * 16 * WSTR + ks * 32);
                acc[n] = __builtin_amdgcn_mfma_f32_16x16x32_bf16(av, bv, acc[n], 0, 0, 0);
            }
        }
#pragma unroll
        for (int n = 0; n < 5; ++n)
#pragma unroll
            for (int j = 0; j < 4; ++j)
                z_s[(wave * 16 + kq * 4 + j) * ZSTR + n * 16 + c15] = acc[n][j];
        __syncthreads();

        // ---- 2) x gather t+1 (latency hides under cell) + cell update ----
        if (t + 1 < NT) load_x(tokens, emb, b0, t + 1, A_s, tid);
#pragma unroll
        for (int ii = 0; ii < 5; ++ii) {
            int idx = tid * 5 + ii;
            int row = idx / HS, h = idx % HS;
            f32x4 z4 = *(f32x4*)(z_s + row * ZSTR + h * 4);
            float zi = z4[0] + b_s[4 * h + 0];
            float zj = z4[1] + b_s[4 * h + 1];
            float zf = z4[2] + b_s[4 * h + 2];
            float zo = z4[3] + b_s[4 * h + 3];
            float co = c_s[idx];
            float fg = sigmoid_fast(zf + 1.f);   // forget bias 1.0
            float ig = sigmoid_fast(zi);
            float og = sigmoid_fast(zo);
            float cn = fg * co + ig * tanh_fast(zj);
            float hn = og * tanh_fast(cn);
            c_s[idx] = cn;
            h_stage[idx] = f2bf(hn);
        }
        __syncthreads();

        // ---- 3) coalesced 8B h strip store + drain ----
        unsigned short* hb = hbuf + (size_t)(t & 1) * (NBATCH * HBSTR);
        store_h(hb, b0, s, h_stage, tid);
        asm volatile("s_waitcnt vmcnt(0)" ::: "memory");
        __syncthreads();

        // ---- 4) raise per-strip flag (agent-scope relaxed store) ----
        if (tid == 0)
            __hip_atomic_store(flags + (size_t)(t * NGRP + g) * 16 + s, 1,
                               __ATOMIC_RELAXED, __HIP_MEMORY_SCOPE_AGENT);

        // ---- 5) overlap window: CE(t-1) while flags propagate ----
        do_ce(t >= 1, t - 1, b0, r0, nr, A_s, U_s, b2, labels, mask,
              ce_arr, llds, lgl, tid);

        // ---- 6) poll the group's 15 flags (backoff, guarded) ----
        if (tid < NSTRIP) {
            const int* fp = flags + (size_t)(t * NGRP + g) * 16 + tid;
            int fv = 0; int gu = 0;
            do {
                fv = __hip_atomic_load(fp, __ATOMIC_RELAXED,
                                       __HIP_MEMORY_SCOPE_AGENT);
                if (!fv) __builtin_amdgcn_s_sleep(1);
            } while (!fv && ++gu < (1 << 17));
        }
        __syncthreads();

        // ---- 7) pull group h slab into A_s ----
        load_h(hb, b0, A_s, tid);
        __syncthreads();
    }

    // ---- CE for final step (h_119 in A_s) ----
    do_ce(true, NT - 1, b0, r0, nr, A_s, U_s, b2, labels, mask,
          ce_arr, llds, lgl, tid);
}

// ---------------------------------------------------------------------------
// Deterministic two-stage reduction: sum(ce) / sum(mask).
// ---------------------------------------------------------------------------
__global__ __launch_bounds__(256)
void reduce1_kernel(const float* __restrict__ ce_arr,
                    const int* __restrict__ mask,
                    float* __restrict__ pce, float* __restrict__ pm)
{
    __shared__ float s_ce[256];
    __shared__ float s_m[256];
    const int tid = threadIdx.x;
    const int lo = blockIdx.x * 480;     // 122880 / 256
    float ac = 0.f, am = 0.f;
    for (int i = lo + tid; i < lo + 480; i += 256) {
        ac += ce_arr[i];
        am += (float)mask[i];
    }
    s_ce[tid] = ac; s_m[tid] = am;
    __syncthreads();
    for (int r = 128; r > 0; r >>= 1) {
        if (tid < r) { s_ce[tid] += s_ce[tid + r]; s_m[tid] += s_m[tid + r]; }
        __syncthreads();
    }
    if (tid == 0) { pce[blockIdx.x] = s_ce[0]; pm[blockIdx.x] = s_m[0]; }
}

__global__ __launch_bounds__(256)
void reduce2_kernel(const float* __restrict__ pce,
                    const float* __restrict__ pm,
                    float* __restrict__ out)
{
    __shared__ float s_ce[256];
    __shared__ float s_m[256];
    const int tid = threadIdx.x;
    s_ce[tid] = pce[tid];
    s_m[tid]  = pm[tid];
    __syncthreads();
    for (int r = 128; r > 0; r >>= 1) {
        if (tid < r) { s_ce[tid] += s_ce[tid + r]; s_m[tid] += s_m[tid + r]; }
        __syncthreads();
    }
    if (tid == 0) out[0] = s_ce[0] / s_m[0];
}

// ---------------------------------------------------------------------------
extern "C" void kernel_launch(void* const* d_in, const int* in_sizes, int n_in,
                              void* d_out, int out_size, void* d_ws, size_t ws_size,
                              hipStream_t stream)
{
    const int*   tokens = (const int*)d_in[0];
    const int*   labels = (const int*)d_in[1];
    const int*   mask   = (const int*)d_in[2];
    const float* emb    = (const float*)d_in[3];
    const float* Wx     = (const float*)d_in[4];
    const float* Wh     = (const float*)d_in[5];
    const float* bias   = (const float*)d_in[6];
    const float* U      = (const float*)d_in[7];
    const float* b2     = (const float*)d_in[8];

    char* wsb = (char*)d_ws;
    unsigned short* Wswz = (unsigned short*)wsb;                      // 844800 B
    unsigned short* hbuf = (unsigned short*)(wsb + 844800);           // 1245184 B
    float* ce    = (float*)(wsb + 2089984);                           // 491520 B
    float* pce   = (float*)(wsb + 2581504);                           // 1024 B
    float* pm    = (float*)(wsb + 2582528);                           // 1024 B
    int*   flags = (int*)(wsb + 2583552);                             // 122880 B

    (void)hipMemsetAsync(flags, 0, 122880, stream);
    wswz_kernel<<<(NSTRIP * SCOL * NKPAD + 255) / 256, 256, 0, stream>>>(Wx, Wh, Wswz);
    lstm_persist<<<NGRP * NSTRIP, 256, 0, stream>>>(
        tokens, labels, mask, emb, bias, U, b2, Wswz, hbuf, ce, flags);
    reduce1_kernel<<<256, 256, 0, stream>>>(ce, mask, pce, pm);
    reduce2_kernel<<<1, 256, 0, stream>>>(pce, pm, (float*)d_out);
}